// Round 7
// baseline (135.875 us; speedup 1.0000x reference)
//
#include <hip/hip_runtime.h>
#include <hip/hip_bf16.h>

typedef float f32x4 __attribute__((ext_vector_type(4)));
typedef short bf16x8 __attribute__((ext_vector_type(8)));
typedef unsigned short u16;
typedef unsigned int u32;

#define NB 32
#define NN 10000
#define DIMX 64

__device__ __forceinline__ u16 f2bf(float f) {
    union { float f; unsigned u; } v; v.f = f;
    unsigned r = (v.u + 0x7FFFu + ((v.u >> 16) & 1u)) >> 16;
    return (u16)r;
}

__device__ __forceinline__ u32 pkbf(float a, float b) {
    __hip_bfloat162 h = __float22bfloat162_rn(make_float2(a, b));
    u32 r; __builtin_memcpy(&r, &h, 4); return r;
}

// ---------------- K1: prep ----------------
__global__ void k_prep(const float* __restrict__ x, const float* __restrict__ n2e_w,
                       const float* __restrict__ n2e_b, const float* __restrict__ e2e_w,
                       const int* __restrict__ ip,
                       float* __restrict__ bias1, u16* __restrict__ w1p, u16* __restrict__ w2p) {
    int id = blockIdx.x * 256 + threadIdx.x;
    if (id < 4096) {
        int b = id >> 7, j = id & 127;
        int i = ip[0];
        const float* xr = x + ((size_t)b * NN + i) * DIMX;
        const float* w = n2e_w + j * 128 + 64;
        float s = n2e_b[j];
        #pragma unroll
        for (int d = 0; d < 64; ++d) s += xr[d] * w[d];
        bias1[b * 128 + j] = s;
    } else if (id < 12288) {
        int e = id - 4096;
        int i8 = e & 7, lane = (e >> 3) & 63, kk = (e >> 9) & 1, t = e >> 10;
        int row = t * 16 + (lane & 15), col = kk * 32 + (lane >> 4) * 8 + i8;
        w1p[e] = f2bf(n2e_w[row * 128 + col]);
    } else if (id < 28672) {
        int e = id - 12288;
        int i8 = e & 7, lane = (e >> 3) & 63, kk = (e >> 9) & 3, t = e >> 11;
        int row = t * 16 + (lane & 15), col = kk * 32 + (lane >> 4) * 8 + i8;
        w2p[e] = f2bf(e2e_w[row * 128 + col]);
    }
}

// ---------------- K2: main fused GEMM1(swapped)+GEMM2+reduce ----------------
// grid = 768 blocks (b = bid/24, qb = bid%24), 4 waves/block.
// 625 subtiles of 16 rows cover exactly 10000 rows. Chunk qb0: 27, else 26.
// WAVE-INDEPENDENT: each wave owns subtile pairs p = wave, wave+4, ... and
// does GEMM1 (2 subs) + GEMM2 (all 8 t2) with acc[2][8] = 64 AGPRs.
// No inner barriers; wave-private 2 KB LDS slice for the h1 round-trip.
// W1 fragments read directly from global (16 KB, L1/L2-hot).
__global__ __launch_bounds__(256, 2) void k_main(
        const float* __restrict__ x, const float* __restrict__ adj,
        const float* __restrict__ bias1, const u16* __restrict__ w1p,
        const u16* __restrict__ w2p, const float* __restrict__ e2e_b,
        float* __restrict__ partials) {
    __shared__ u16 sW2[16384];    // 32 KB
    __shared__ u16 sH1[4096];     // 8 KB: 4 waves * 2 subs * 1 KB slice
    __shared__ float sBias[128];  // bias1 row b

    const int tid = threadIdx.x;
    const int lane = tid & 63, wave = tid >> 6;
    const int c = lane & 15, g = lane >> 4;
    const int bid = blockIdx.x;
    const int b = bid / 24, qb = bid - b * 24;
    const int s0 = qb ? 27 + (qb - 1) * 26 : 0;
    const int cnt = qb ? 26 : 27;
    const int npairs = (cnt + 1) >> 1;   // 13 or 14

    #pragma unroll
    for (int p = 0; p < 8; ++p) { int o = (p * 256 + tid) * 8;
        *(bf16x8*)&sW2[o] = *(const bf16x8*)&w2p[o]; }
    if (tid < 128) sBias[tid] = bias1[b * 128 + tid];

    float b2v[8];
    #pragma unroll
    for (int t2 = 0; t2 < 8; ++t2) b2v[t2] = e2e_b[t2 * 16 + c];

    float sAcc[8] = {0.f,0.f,0.f,0.f,0.f,0.f,0.f,0.f};
    __syncthreads();

    const size_t xbatch = (size_t)b * NN;
    const bf16x8* const gW1 = (const bf16x8*)w1p;   // fragment-packed, global
    u16* const myH = &sH1[wave * 1024];             // 2 KB slice (u16 units)

    for (int p = wave; p < npairs; p += 4) {
        // ---- adj + x fragments for my 2 subtiles ----
        f32x4 adjv[2];
        bf16x8 A1[2][2];
        #pragma unroll
        for (int s = 0; s < 2; ++s) {
            int idx = 2 * p + s;
            int valid = idx < cnt;
            int stl = valid ? idx : cnt - 1;
            int row0 = (s0 + stl) * 16;
            if (valid) adjv[s] = *(const f32x4*)(adj + row0 + 4 * g);
            else adjv[s] = (f32x4){0.f,0.f,0.f,0.f};
            const float* xr = x + (xbatch + row0 + c) * 64 + g * 8;
            #pragma unroll
            for (int kk = 0; kk < 2; ++kk) {
                f32x4 lo = *(const f32x4*)(xr + kk * 32);
                f32x4 hi = *(const f32x4*)(xr + kk * 32 + 4);
                union { bf16x8 v; u32 w[4]; } u;
                u.w[0] = pkbf(lo[0], lo[1]); u.w[1] = pkbf(lo[2], lo[3]);
                u.w[2] = pkbf(hi[0], hi[1]); u.w[3] = pkbf(hi[2], hi[3]);
                A1[s][kk] = u.v;
            }
        }

        f32x4 acc[2][8];   // 64 AGPRs
        #pragma unroll
        for (int s = 0; s < 2; ++s)
            #pragma unroll
            for (int t2 = 0; t2 < 8; ++t2) acc[s][t2] = (f32x4){0.f,0.f,0.f,0.f};

        #pragma unroll
        for (int kk2 = 0; kk2 < 4; ++kk2) {
            const int t0 = kk2 * 2, t1 = kk2 * 2 + 1;
            // W1 fragments straight from global (coalesced 16B/lane, L1-hot)
            bf16x8 w1a0 = gW1[(t0 * 2 + 0) * 64 + lane];
            bf16x8 w1b0 = gW1[(t0 * 2 + 1) * 64 + lane];
            bf16x8 w1a1 = gW1[(t1 * 2 + 0) * 64 + lane];
            bf16x8 w1b1 = gW1[(t1 * 2 + 1) * 64 + lane];
            f32x4 cb0 = *(const f32x4*)&sBias[t0 * 16 + 4 * g];
            f32x4 cb1 = *(const f32x4*)&sBias[t1 * 16 + 4 * g];
            // GEMM1 (swapped): lane holds h1[n=c][j1=16t+4g+r]
            #pragma unroll
            for (int s = 0; s < 2; ++s) {
                f32x4 d0 = __builtin_amdgcn_mfma_f32_16x16x32_bf16(w1a0, A1[s][0], cb0, 0, 0, 0);
                d0 = __builtin_amdgcn_mfma_f32_16x16x32_bf16(w1b0, A1[s][1], d0, 0, 0, 0);
                f32x4 d1 = __builtin_amdgcn_mfma_f32_16x16x32_bf16(w1a1, A1[s][0], cb1, 0, 0, 0);
                d1 = __builtin_amdgcn_mfma_f32_16x16x32_bf16(w1b1, A1[s][1], d1, 0, 0, 0);
                u32 p00 = pkbf(fmaxf(d0[0], 0.f), fmaxf(d0[1], 0.f));
                u32 p01 = pkbf(fmaxf(d0[2], 0.f), fmaxf(d0[3], 0.f));
                u32 p10 = pkbf(fmaxf(d1[0], 0.f), fmaxf(d1[1], 0.f));
                u32 p11 = pkbf(fmaxf(d1[2], 0.f), fmaxf(d1[3], 0.f));
                int base = s * 1024 + c * 64;   // byte offset in my slice
                int swz = 16 * (c & 3);
                *(uint2*)&myH[(base + ((8 * g) ^ swz)) >> 1]      = make_uint2(p00, p01);
                *(uint2*)&myH[(base + ((32 + 8 * g) ^ swz)) >> 1] = make_uint2(p10, p11);
            }
            // same-wave readback (lgkmcnt only, no barrier), then GEMM2
            bf16x8 A2[2];
            #pragma unroll
            for (int s = 0; s < 2; ++s)
                A2[s] = *(const bf16x8*)&myH[(s * 1024 + c * 64 + 16 * (g ^ (c & 3))) >> 1];
            #pragma unroll
            for (int t2 = 0; t2 < 8; ++t2) {
                bf16x8 w2f = *(const bf16x8*)&sW2[(t2 * 4 + kk2) * 512 + lane * 8];
                acc[0][t2] = __builtin_amdgcn_mfma_f32_16x16x32_bf16(A2[0], w2f, acc[0][t2], 0, 0, 0);
                acc[1][t2] = __builtin_amdgcn_mfma_f32_16x16x32_bf16(A2[1], w2f, acc[1][t2], 0, 0, 0);
            }
        }

        // ---- epilogue: bias2 + relu, adj-weighted row sum ----
        #pragma unroll
        for (int t2 = 0; t2 < 8; ++t2) {
            float bb = b2v[t2];
            #pragma unroll
            for (int s = 0; s < 2; ++s)
                #pragma unroll
                for (int r = 0; r < 4; ++r)
                    sAcc[t2] = fmaf(adjv[s][r], fmaxf(acc[s][t2][r] + bb, 0.f), sAcc[t2]);
        }
    }

    // reduce over lane-groups (g), then across waves
    #pragma unroll
    for (int t2 = 0; t2 < 8; ++t2) {
        float v = sAcc[t2];
        v += __shfl_xor(v, 16, 64);
        v += __shfl_xor(v, 32, 64);
        sAcc[t2] = v;
    }
    __syncthreads();
    float* sRed = (float*)sH1;   // reuse h1 LDS (2 KB needed of 8 KB)
    if (lane < 16) {
        #pragma unroll
        for (int t2 = 0; t2 < 8; ++t2) sRed[wave * 128 + t2 * 16 + lane] = sAcc[t2];
    }
    __syncthreads();
    if (tid < 128) {
        float v = 0.f;
        #pragma unroll
        for (int w = 0; w < 4; ++w) v += sRed[w * 128 + tid];
        partials[bid * 128 + tid] = v;
    }
}

// ---------------- K3: final small MLP ----------------
__global__ void k_final(const float* __restrict__ partials, const float* __restrict__ x,
                        const int* __restrict__ ip,
                        const float* __restrict__ e2n_w, const float* __restrict__ e2n_b,
                        const float* __restrict__ n2n_w, const float* __restrict__ n2n_b,
                        const float* __restrict__ out_w, const float* __restrict__ out_b,
                        float* __restrict__ out) {
    int b = blockIdx.x, j = threadIdx.x;  // 128 threads
    __shared__ float s0[128], s1[128], s2[128];
    float acc = 0.f;
    #pragma unroll
    for (int qq = 0; qq < 24; ++qq) acc += partials[(b * 24 + qq) * 128 + j];
    s0[j] = acc;
    __syncthreads();
    {
        float a1 = e2n_b[j];
        const float* w = e2n_w + j * 128;
        #pragma unroll 8
        for (int k = 0; k < 128; ++k) a1 += w[k] * s0[k];
        s1[j] = fmaxf(a1, 0.f);
    }
    __syncthreads();
    {
        float a2 = n2n_b[j];
        const float* w = n2n_w + j * 128;
        #pragma unroll 8
        for (int k = 0; k < 128; ++k) a2 += w[k] * s1[k];
        s2[j] = fmaxf(a2, 0.f);
    }
    __syncthreads();
    if (j < 64) {
        int i = ip[0];
        const float* xr = x + ((size_t)b * NN + i) * DIMX;
        const float* ow = out_w + j * 192;
        float o = out_b[j];
        #pragma unroll 8
        for (int m = 0; m < 64; ++m) o += ow[m] * xr[m];
        #pragma unroll 8
        for (int m = 0; m < 128; ++m) o += ow[64 + m] * s2[m];
        out[b * 64 + j] = o;
    }
}

extern "C" void kernel_launch(void* const* d_in, const int* in_sizes, int n_in,
                              void* d_out, int out_size, void* d_ws, size_t ws_size,
                              hipStream_t stream) {
    const float* x      = (const float*)d_in[0];
    const float* adj    = (const float*)d_in[1];
    const float* n2e_w  = (const float*)d_in[2];
    const float* n2e_b  = (const float*)d_in[3];
    const float* e2e_w  = (const float*)d_in[4];
    const float* e2e_b  = (const float*)d_in[5];
    const float* e2n_w  = (const float*)d_in[6];
    const float* e2n_b  = (const float*)d_in[7];
    const float* n2n_w  = (const float*)d_in[8];
    const float* n2n_b  = (const float*)d_in[9];
    const float* out_w  = (const float*)d_in[10];
    const float* out_b  = (const float*)d_in[11];
    const int*   ip     = (const int*)d_in[12];
    float* out = (float*)d_out;

    char* ws = (char*)d_ws;
    float* bias1    = (float*)ws;               // 16384 B
    u16*   w1p      = (u16*)(ws + 16384);       // 16384 B
    u16*   w2p      = (u16*)(ws + 32768);       // 32768 B
    float* partials = (float*)(ws + 65536);     // 393216 B (768 blocks * 128 f32)

    k_prep<<<112, 256, 0, stream>>>(x, n2e_w, n2e_b, e2e_w, ip, bias1, w1p, w2p);
    k_main<<<768, 256, 0, stream>>>(x, adj, bias1, w1p, w2p, e2e_b, partials);
    k_final<<<32, 128, 0, stream>>>(partials, x, ip, e2n_w, e2n_b, n2n_w, n2n_b,
                                    out_w, out_b, out);
}

// Round 8
// 119.451 us; speedup vs baseline: 1.1375x; 1.1375x over previous
//
#include <hip/hip_runtime.h>
#include <hip/hip_bf16.h>

typedef float f32x4 __attribute__((ext_vector_type(4)));
typedef short bf16x8 __attribute__((ext_vector_type(8)));
typedef unsigned short u16;
typedef unsigned int u32;

#define NB 32
#define NN 10000
#define DIMX 64

__device__ __forceinline__ u16 f2bf(float f) {
    union { float f; unsigned u; } v; v.f = f;
    unsigned r = (v.u + 0x7FFFu + ((v.u >> 16) & 1u)) >> 16;
    return (u16)r;
}

__device__ __forceinline__ u32 pkbf(float a, float b) {
    __hip_bfloat162 h = __float22bfloat162_rn(make_float2(a, b));
    u32 r; __builtin_memcpy(&r, &h, 4); return r;
}

// ---------------- K1: prep ----------------
__global__ void k_prep(const float* __restrict__ x, const float* __restrict__ n2e_w,
                       const float* __restrict__ n2e_b, const float* __restrict__ e2e_w,
                       const int* __restrict__ ip,
                       float* __restrict__ bias1, u16* __restrict__ w1p, u16* __restrict__ w2p) {
    int id = blockIdx.x * 256 + threadIdx.x;
    if (id < 4096) {
        int b = id >> 7, j = id & 127;
        int i = ip[0];
        const float* xr = x + ((size_t)b * NN + i) * DIMX;
        const float* w = n2e_w + j * 128 + 64;
        float s = n2e_b[j];
        #pragma unroll
        for (int d = 0; d < 64; ++d) s += xr[d] * w[d];
        bias1[b * 128 + j] = s;
    } else if (id < 12288) {
        int e = id - 4096;
        int i8 = e & 7, lane = (e >> 3) & 63, kk = (e >> 9) & 1, t = e >> 10;
        int row = t * 16 + (lane & 15), col = kk * 32 + (lane >> 4) * 8 + i8;
        w1p[e] = f2bf(n2e_w[row * 128 + col]);
    } else if (id < 28672) {
        int e = id - 12288;
        int i8 = e & 7, lane = (e >> 3) & 63, kk = (e >> 9) & 3, t = e >> 11;
        int row = t * 16 + (lane & 15), col = kk * 32 + (lane >> 4) * 8 + i8;
        w2p[e] = f2bf(e2e_w[row * 128 + col]);
    }
}

// ---------------- K2: main fused GEMM1(swapped)+GEMM2+reduce ----------------
// grid = 512 blocks (b = bid>>4, qb = bid&15), 4 waves/block, 2 blocks/CU.
// Chunk qb0: 40 subtiles, else 39 (16x39+40 = 664... actually 40+15*39 = 625
// subtiles of 16 rows = exactly 10000 rows). npairs == 20 for both.
// WAVE-INDEPENDENT main loop: each wave owns pairs p = wave, wave+4, ... (5
// iterations), GEMM1 for 2 subtiles + GEMM2 for all 8 t2, acc[2][8] = 64
// AGPRs. W1/W2 staged in LDS; wave-private 2 KB h1 slice; NO main-loop
// barriers.
__global__ __launch_bounds__(256, 2) void k_main(
        const float* __restrict__ x, const float* __restrict__ adj,
        const float* __restrict__ bias1, const u16* __restrict__ w1p,
        const u16* __restrict__ w2p, const float* __restrict__ e2e_b,
        float* __restrict__ partials) {
    __shared__ u16 sW1[8192];     // 16 KB
    __shared__ u16 sW2[16384];    // 32 KB
    __shared__ u16 sH1[4096];     // 8 KB: 4 waves * 2 subs * 1 KB slice
    __shared__ float sBias[128];  // bias1 row b

    const int tid = threadIdx.x;
    const int lane = tid & 63, wave = tid >> 6;
    const int c = lane & 15, g = lane >> 4;
    const int bid = blockIdx.x;
    const int b = bid >> 4, qb = bid & 15;
    const int s0 = qb ? qb * 39 + 1 : 0;
    const int cnt = qb ? 39 : 40;

    #pragma unroll
    for (int p = 0; p < 4; ++p) { int o = (p * 256 + tid) * 8;
        *(bf16x8*)&sW1[o] = *(const bf16x8*)&w1p[o]; }
    #pragma unroll
    for (int p = 0; p < 8; ++p) { int o = (p * 256 + tid) * 8;
        *(bf16x8*)&sW2[o] = *(const bf16x8*)&w2p[o]; }
    if (tid < 128) sBias[tid] = bias1[b * 128 + tid];

    float b2v[8];
    #pragma unroll
    for (int t2 = 0; t2 < 8; ++t2) b2v[t2] = e2e_b[t2 * 16 + c];

    float sAcc[8] = {0.f,0.f,0.f,0.f,0.f,0.f,0.f,0.f};
    __syncthreads();

    const size_t xbatch = (size_t)b * NN;
    u16* const myH = &sH1[wave * 1024];   // 2 KB wave-private slice (u16 units)

    #pragma unroll 1
    for (int p = wave; p < 20; p += 4) {
        // ---- adj + x fragments for my 2 subtiles ----
        f32x4 adjv[2];
        bf16x8 A1[2][2];
        #pragma unroll
        for (int s = 0; s < 2; ++s) {
            int idx = 2 * p + s;
            int valid = idx < cnt;
            int stl = valid ? idx : cnt - 1;
            int row0 = (s0 + stl) * 16;
            if (valid) adjv[s] = *(const f32x4*)(adj + row0 + 4 * g);
            else adjv[s] = (f32x4){0.f,0.f,0.f,0.f};
            const float* xr = x + (xbatch + row0 + c) * 64 + g * 8;
            #pragma unroll
            for (int kk = 0; kk < 2; ++kk) {
                f32x4 lo = *(const f32x4*)(xr + kk * 32);
                f32x4 hi = *(const f32x4*)(xr + kk * 32 + 4);
                union { bf16x8 v; u32 w[4]; } u;
                u.w[0] = pkbf(lo[0], lo[1]); u.w[1] = pkbf(lo[2], lo[3]);
                u.w[2] = pkbf(hi[0], hi[1]); u.w[3] = pkbf(hi[2], hi[3]);
                A1[s][kk] = u.v;
            }
        }

        f32x4 acc[2][8];   // 64 AGPRs
        #pragma unroll
        for (int s = 0; s < 2; ++s)
            #pragma unroll
            for (int t2 = 0; t2 < 8; ++t2) acc[s][t2] = (f32x4){0.f,0.f,0.f,0.f};

        #pragma unroll
        for (int kk2 = 0; kk2 < 4; ++kk2) {
            const int t0 = kk2 * 2, t1 = kk2 * 2 + 1;
            // W1 fragments from LDS (transient, low-latency)
            bf16x8 w1a0 = *(const bf16x8*)&sW1[(t0 * 2 + 0) * 512 + lane * 8];
            bf16x8 w1b0 = *(const bf16x8*)&sW1[(t0 * 2 + 1) * 512 + lane * 8];
            bf16x8 w1a1 = *(const bf16x8*)&sW1[(t1 * 2 + 0) * 512 + lane * 8];
            bf16x8 w1b1 = *(const bf16x8*)&sW1[(t1 * 2 + 1) * 512 + lane * 8];
            f32x4 cb0 = *(const f32x4*)&sBias[t0 * 16 + 4 * g];
            f32x4 cb1 = *(const f32x4*)&sBias[t1 * 16 + 4 * g];
            // GEMM1 (swapped): lane holds h1[n=c][j1=16t+4g+r]
            #pragma unroll
            for (int s = 0; s < 2; ++s) {
                f32x4 d0 = __builtin_amdgcn_mfma_f32_16x16x32_bf16(w1a0, A1[s][0], cb0, 0, 0, 0);
                d0 = __builtin_amdgcn_mfma_f32_16x16x32_bf16(w1b0, A1[s][1], d0, 0, 0, 0);
                f32x4 d1 = __builtin_amdgcn_mfma_f32_16x16x32_bf16(w1a1, A1[s][0], cb1, 0, 0, 0);
                d1 = __builtin_amdgcn_mfma_f32_16x16x32_bf16(w1b1, A1[s][1], d1, 0, 0, 0);
                u32 p00 = pkbf(fmaxf(d0[0], 0.f), fmaxf(d0[1], 0.f));
                u32 p01 = pkbf(fmaxf(d0[2], 0.f), fmaxf(d0[3], 0.f));
                u32 p10 = pkbf(fmaxf(d1[0], 0.f), fmaxf(d1[1], 0.f));
                u32 p11 = pkbf(fmaxf(d1[2], 0.f), fmaxf(d1[3], 0.f));
                int base = s * 1024 + c * 64;   // byte offset in my slice
                int swz = 16 * (c & 3);
                *(uint2*)&myH[(base + ((8 * g) ^ swz)) >> 1]      = make_uint2(p00, p01);
                *(uint2*)&myH[(base + ((32 + 8 * g) ^ swz)) >> 1] = make_uint2(p10, p11);
            }
            // same-wave readback (lgkmcnt ordering only, no barrier)
            bf16x8 A2[2];
            #pragma unroll
            for (int s = 0; s < 2; ++s)
                A2[s] = *(const bf16x8*)&myH[(s * 1024 + c * 64 + 16 * (g ^ (c & 3))) >> 1];
            #pragma unroll
            for (int t2 = 0; t2 < 8; ++t2) {
                bf16x8 w2f = *(const bf16x8*)&sW2[(t2 * 4 + kk2) * 512 + lane * 8];
                acc[0][t2] = __builtin_amdgcn_mfma_f32_16x16x32_bf16(A2[0], w2f, acc[0][t2], 0, 0, 0);
                acc[1][t2] = __builtin_amdgcn_mfma_f32_16x16x32_bf16(A2[1], w2f, acc[1][t2], 0, 0, 0);
            }
        }

        // ---- epilogue: bias2 + relu, adj-weighted row sum ----
        #pragma unroll
        for (int t2 = 0; t2 < 8; ++t2) {
            float bb = b2v[t2];
            #pragma unroll
            for (int s = 0; s < 2; ++s)
                #pragma unroll
                for (int r = 0; r < 4; ++r)
                    sAcc[t2] = fmaf(adjv[s][r], fmaxf(acc[s][t2][r] + bb, 0.f), sAcc[t2]);
        }
    }

    // reduce over lane-groups (g), then across waves
    #pragma unroll
    for (int t2 = 0; t2 < 8; ++t2) {
        float v = sAcc[t2];
        v += __shfl_xor(v, 16, 64);
        v += __shfl_xor(v, 32, 64);
        sAcc[t2] = v;
    }
    __syncthreads();
    float* sRed = (float*)sW2;   // reuse weight LDS for the final reduction
    if (lane < 16) {
        #pragma unroll
        for (int t2 = 0; t2 < 8; ++t2) sRed[wave * 128 + t2 * 16 + lane] = sAcc[t2];
    }
    __syncthreads();
    if (tid < 128) {
        float v = 0.f;
        #pragma unroll
        for (int w = 0; w < 4; ++w) v += sRed[w * 128 + tid];
        partials[bid * 128 + tid] = v;
    }
}

// ---------------- K3: final small MLP ----------------
__global__ void k_final(const float* __restrict__ partials, const float* __restrict__ x,
                        const int* __restrict__ ip,
                        const float* __restrict__ e2n_w, const float* __restrict__ e2n_b,
                        const float* __restrict__ n2n_w, const float* __restrict__ n2n_b,
                        const float* __restrict__ out_w, const float* __restrict__ out_b,
                        float* __restrict__ out) {
    int b = blockIdx.x, j = threadIdx.x;  // 128 threads
    __shared__ float s0[128], s1[128], s2[128];
    float acc = 0.f;
    #pragma unroll
    for (int qq = 0; qq < 16; ++qq) acc += partials[(b * 16 + qq) * 128 + j];
    s0[j] = acc;
    __syncthreads();
    {
        float a1 = e2n_b[j];
        const float* w = e2n_w + j * 128;
        #pragma unroll 8
        for (int k = 0; k < 128; ++k) a1 += w[k] * s0[k];
        s1[j] = fmaxf(a1, 0.f);
    }
    __syncthreads();
    {
        float a2 = n2n_b[j];
        const float* w = n2n_w + j * 128;
        #pragma unroll 8
        for (int k = 0; k < 128; ++k) a2 += w[k] * s1[k];
        s2[j] = fmaxf(a2, 0.f);
    }
    __syncthreads();
    if (j < 64) {
        int i = ip[0];
        const float* xr = x + ((size_t)b * NN + i) * DIMX;
        const float* ow = out_w + j * 192;
        float o = out_b[j];
        #pragma unroll 8
        for (int m = 0; m < 64; ++m) o += ow[m] * xr[m];
        #pragma unroll 8
        for (int m = 0; m < 128; ++m) o += ow[64 + m] * s2[m];
        out[b * 64 + j] = o;
    }
}

extern "C" void kernel_launch(void* const* d_in, const int* in_sizes, int n_in,
                              void* d_out, int out_size, void* d_ws, size_t ws_size,
                              hipStream_t stream) {
    const float* x      = (const float*)d_in[0];
    const float* adj    = (const float*)d_in[1];
    const float* n2e_w  = (const float*)d_in[2];
    const float* n2e_b  = (const float*)d_in[3];
    const float* e2e_w  = (const float*)d_in[4];
    const float* e2e_b  = (const float*)d_in[5];
    const float* e2n_w  = (const float*)d_in[6];
    const float* e2n_b  = (const float*)d_in[7];
    const float* n2n_w  = (const float*)d_in[8];
    const float* n2n_b  = (const float*)d_in[9];
    const float* out_w  = (const float*)d_in[10];
    const float* out_b  = (const float*)d_in[11];
    const int*   ip     = (const int*)d_in[12];
    float* out = (float*)d_out;

    char* ws = (char*)d_ws;
    float* bias1    = (float*)ws;               // 16384 B
    u16*   w1p      = (u16*)(ws + 16384);       // 16384 B
    u16*   w2p      = (u16*)(ws + 32768);       // 32768 B
    float* partials = (float*)(ws + 65536);     // 262144 B (512 blocks * 128 f32)

    k_prep<<<112, 256, 0, stream>>>(x, n2e_w, n2e_b, e2e_w, ip, bias1, w1p, w2p);
    k_main<<<512, 256, 0, stream>>>(x, adj, bias1, w1p, w2p, e2e_b, partials);
    k_final<<<32, 128, 0, stream>>>(partials, x, ip, e2n_w, e2n_b, n2n_w, n2n_b,
                                    out_w, out_b, out);
}

// Round 9
// 48.960 us; speedup vs baseline: 2.7752x; 2.4398x over previous
//
#include <hip/hip_runtime.h>
#include <hip/hip_bf16.h>

typedef float f32x4 __attribute__((ext_vector_type(4)));
typedef short bf16x8 __attribute__((ext_vector_type(8)));
typedef unsigned short u16;
typedef unsigned int u32;

#define NB 32
#define NN 10000
#define DIMX 64

__device__ __forceinline__ u16 f2bf(float f) {
    union { float f; unsigned u; } v; v.f = f;
    unsigned r = (v.u + 0x7FFFu + ((v.u >> 16) & 1u)) >> 16;
    return (u16)r;
}

__device__ __forceinline__ u32 pkbf(float a, float b) {
    __hip_bfloat162 h = __float22bfloat162_rn(make_float2(a, b));
    u32 r; __builtin_memcpy(&r, &h, 4); return r;
}

// ---------------- K1: prep ----------------
__global__ void k_prep(const float* __restrict__ x, const float* __restrict__ n2e_w,
                       const float* __restrict__ n2e_b, const float* __restrict__ e2e_w,
                       const int* __restrict__ ip,
                       float* __restrict__ bias1, u16* __restrict__ w1p, u16* __restrict__ w2p) {
    int id = blockIdx.x * 256 + threadIdx.x;
    if (id < 4096) {
        int b = id >> 7, j = id & 127;
        int i = ip[0];
        const float* xr = x + ((size_t)b * NN + i) * DIMX;
        const float* w = n2e_w + j * 128 + 64;
        float s = n2e_b[j];
        #pragma unroll
        for (int d = 0; d < 64; ++d) s += xr[d] * w[d];
        bias1[b * 128 + j] = s;
    } else if (id < 12288) {
        int e = id - 4096;
        int i8 = e & 7, lane = (e >> 3) & 63, kk = (e >> 9) & 1, t = e >> 10;
        int row = t * 16 + (lane & 15), col = kk * 32 + (lane >> 4) * 8 + i8;
        w1p[e] = f2bf(n2e_w[row * 128 + col]);
    } else if (id < 28672) {
        int e = id - 12288;
        int i8 = e & 7, lane = (e >> 3) & 63, kk = (e >> 9) & 3, t = e >> 11;
        int row = t * 16 + (lane & 15), col = kk * 32 + (lane >> 4) * 8 + i8;
        w2p[e] = f2bf(e2e_w[row * 128 + col]);
    }
}

// ---------------- K2: main fused GEMM1(swapped)+GEMM2+reduce ----------------
// ROUND-6 STRUCTURE (proven clean): grid = 512 blocks (b = bid>>4, qb =
// bid&15), 4 waves/block, 2 blocks/CU. Waves cooperate in PAIRS over 4
// subtiles/iter: each wave does GEMM1 for 2 subtiles (h1 shared via LDS,
// parity double-buffered, 1 barrier per kk2) and GEMM2 for 4 of the 8 t2.
// acc[4][4] = 64 AGPRs.
// Round-9 deltas: (1) next-iteration x prefetch held in 32 f32 regs across
// the kk2 loop; (2) adj loads moved to the epilogue; (3) e2e_b read from LDS
// at the epilogue instead of living in registers.
__global__ __launch_bounds__(256, 2) void k_main(
        const float* __restrict__ x, const float* __restrict__ adj,
        const float* __restrict__ bias1, const u16* __restrict__ w1p,
        const u16* __restrict__ w2p, const float* __restrict__ e2e_b,
        float* __restrict__ partials) {
    __shared__ u16 sW1[8192];     // 16 KB
    __shared__ u16 sW2[16384];    // 32 KB
    __shared__ u16 sH1[8192];     // 16 KB: [pair][parity][sub4][512 u16]
    __shared__ float sBias[256];  // [0:128) bias1 row b, [128:256) e2e_b

    const int tid = threadIdx.x;
    const int lane = tid & 63, wave = tid >> 6;
    const int c = lane & 15, g = lane >> 4;
    const int pair = wave >> 1, wh = wave & 1;
    const int bid = blockIdx.x;
    const int b = bid >> 4, qb = bid & 15;
    const int s0 = qb ? qb * 39 + 1 : 0;
    const int cnt = qb ? 39 : 40;

    #pragma unroll
    for (int p = 0; p < 4; ++p) { int o = (p * 256 + tid) * 8;
        *(bf16x8*)&sW1[o] = *(const bf16x8*)&w1p[o]; }
    #pragma unroll
    for (int p = 0; p < 8; ++p) { int o = (p * 256 + tid) * 8;
        *(bf16x8*)&sW2[o] = *(const bf16x8*)&w2p[o]; }
    if (tid < 128) sBias[tid] = bias1[b * 128 + tid];
    else if (tid < 256) sBias[tid] = e2e_b[tid - 128];

    float sAcc[4] = {0.f,0.f,0.f,0.f};
    __syncthreads();

    const size_t xbatch = (size_t)b * NN;
    u16* const pairH = &sH1[pair * 4096];   // 8 KB per pair (u16 units)

    // ---- prefetch iteration 0's x (2 subtiles, 4 f32x4 each) ----
    f32x4 xl[2][4];
    #pragma unroll
    for (int s = 0; s < 2; ++s) {
        int idx = pair * 4 + wh * 2 + s;
        int stl = idx < cnt ? idx : cnt - 1;
        const float* xr = x + (xbatch + (s0 + stl) * 16 + c) * 64 + g * 8;
        xl[s][0] = *(const f32x4*)(xr);
        xl[s][1] = *(const f32x4*)(xr + 4);
        xl[s][2] = *(const f32x4*)(xr + 32);
        xl[s][3] = *(const f32x4*)(xr + 36);
    }

    #pragma unroll 1
    for (int it = 0; it < 5; ++it) {
        const int base_idx = it * 8 + pair * 4;

        // ---- convert prefetched x to bf16 fragments ----
        bf16x8 A1[2][2];
        #pragma unroll
        for (int s = 0; s < 2; ++s)
            #pragma unroll
            for (int kk = 0; kk < 2; ++kk) {
                f32x4 lo = xl[s][kk * 2], hi = xl[s][kk * 2 + 1];
                union { bf16x8 v; u32 w[4]; } u;
                u.w[0] = pkbf(lo[0], lo[1]); u.w[1] = pkbf(lo[2], lo[3]);
                u.w[2] = pkbf(hi[0], hi[1]); u.w[3] = pkbf(hi[2], hi[3]);
                A1[s][kk] = u.v;
            }

        // ---- issue next iteration's x loads (hidden under kk2 loop) ----
        if (it < 4) {
            int nbase = (it + 1) * 8 + pair * 4;
            #pragma unroll
            for (int s = 0; s < 2; ++s) {
                int idx = nbase + wh * 2 + s;
                int stl = idx < cnt ? idx : cnt - 1;
                const float* xr = x + (xbatch + (s0 + stl) * 16 + c) * 64 + g * 8;
                xl[s][0] = *(const f32x4*)(xr);
                xl[s][1] = *(const f32x4*)(xr + 4);
                xl[s][2] = *(const f32x4*)(xr + 32);
                xl[s][3] = *(const f32x4*)(xr + 36);
            }
        }

        f32x4 acc[4][4];   // [sub][tt] -> 64 AGPRs
        #pragma unroll
        for (int sub = 0; sub < 4; ++sub)
            #pragma unroll
            for (int tt = 0; tt < 4; ++tt) acc[sub][tt] = (f32x4){0.f,0.f,0.f,0.f};

        #pragma unroll
        for (int kk2 = 0; kk2 < 4; ++kk2) {
            u16* const bufH = pairH + (kk2 & 1) * 2048;   // parity buffer (4 KB)
            const int t0 = kk2 * 2, t1 = kk2 * 2 + 1;
            bf16x8 w1a0 = *(const bf16x8*)&sW1[(t0 * 2 + 0) * 512 + lane * 8];
            bf16x8 w1b0 = *(const bf16x8*)&sW1[(t0 * 2 + 1) * 512 + lane * 8];
            bf16x8 w1a1 = *(const bf16x8*)&sW1[(t1 * 2 + 0) * 512 + lane * 8];
            bf16x8 w1b1 = *(const bf16x8*)&sW1[(t1 * 2 + 1) * 512 + lane * 8];
            f32x4 cb0 = *(const f32x4*)&sBias[t0 * 16 + 4 * g];
            f32x4 cb1 = *(const f32x4*)&sBias[t1 * 16 + 4 * g];
            // GEMM1 (swapped) for my 2 subtiles: lane holds h1[n=c][j1=16t+4g+r]
            #pragma unroll
            for (int s = 0; s < 2; ++s) {
                f32x4 d0 = __builtin_amdgcn_mfma_f32_16x16x32_bf16(w1a0, A1[s][0], cb0, 0, 0, 0);
                d0 = __builtin_amdgcn_mfma_f32_16x16x32_bf16(w1b0, A1[s][1], d0, 0, 0, 0);
                f32x4 d1 = __builtin_amdgcn_mfma_f32_16x16x32_bf16(w1a1, A1[s][0], cb1, 0, 0, 0);
                d1 = __builtin_amdgcn_mfma_f32_16x16x32_bf16(w1b1, A1[s][1], d1, 0, 0, 0);
                u32 p00 = pkbf(fmaxf(d0[0], 0.f), fmaxf(d0[1], 0.f));
                u32 p01 = pkbf(fmaxf(d0[2], 0.f), fmaxf(d0[3], 0.f));
                u32 p10 = pkbf(fmaxf(d1[0], 0.f), fmaxf(d1[1], 0.f));
                u32 p11 = pkbf(fmaxf(d1[2], 0.f), fmaxf(d1[3], 0.f));
                int slice = (wh * 2 + s) * 512;            // u16 units (1 KB slice)
                int base = c * 64;                          // byte offset within slice
                int swz = 16 * (c & 3);
                *(uint2*)&bufH[slice + ((base + ((8 * g) ^ swz)) >> 1)]      = make_uint2(p00, p01);
                *(uint2*)&bufH[slice + ((base + ((32 + 8 * g) ^ swz)) >> 1)] = make_uint2(p10, p11);
            }
            __syncthreads();
            // read A2 fragments for the pair's 4 subtiles; GEMM2 for my 4 t2
            bf16x8 A2[4];
            #pragma unroll
            for (int sub = 0; sub < 4; ++sub)
                A2[sub] = *(const bf16x8*)&bufH[sub * 512 + ((c * 64 + 16 * (g ^ (c & 3))) >> 1)];
            #pragma unroll
            for (int tt = 0; tt < 4; ++tt) {
                const int t2 = wh * 4 + tt;
                bf16x8 w2f = *(const bf16x8*)&sW2[(t2 * 4 + kk2) * 512 + lane * 8];
                #pragma unroll
                for (int sub = 0; sub < 4; ++sub)
                    acc[sub][tt] = __builtin_amdgcn_mfma_f32_16x16x32_bf16(A2[sub], w2f, acc[sub][tt], 0, 0, 0);
            }
        }

        // ---- epilogue: adj + bias2 loaded here (not live in the loop) ----
        f32x4 adjv[4];
        #pragma unroll
        for (int sub = 0; sub < 4; ++sub) {
            int idx = base_idx + sub;
            if (idx < cnt) adjv[sub] = *(const f32x4*)(adj + (s0 + idx) * 16 + 4 * g);
            else adjv[sub] = (f32x4){0.f,0.f,0.f,0.f};
        }
        #pragma unroll
        for (int tt = 0; tt < 4; ++tt) {
            float bb = sBias[128 + (wh * 4 + tt) * 16 + c];
            #pragma unroll
            for (int sub = 0; sub < 4; ++sub)
                #pragma unroll
                for (int r = 0; r < 4; ++r)
                    sAcc[tt] = fmaf(adjv[sub][r], fmaxf(acc[sub][tt][r] + bb, 0.f), sAcc[tt]);
        }
    }

    // reduce over lane-groups (g), then across waves
    #pragma unroll
    for (int tt = 0; tt < 4; ++tt) {
        float v = sAcc[tt];
        v += __shfl_xor(v, 16, 64);
        v += __shfl_xor(v, 32, 64);
        sAcc[tt] = v;
    }
    __syncthreads();
    float* sRed = (float*)sW1;   // reuse weight LDS for the final reduction
    if (lane < 16) {
        #pragma unroll
        for (int tt = 0; tt < 4; ++tt) sRed[wave * 64 + tt * 16 + lane] = sAcc[tt];
    }
    __syncthreads();
    if (tid < 128) {
        int t2 = tid >> 4, jc = tid & 15;
        int tt = t2 & 3, w0 = t2 >> 2;   // t2<4 -> waves 0,2 ; t2>=4 -> waves 1,3
        partials[bid * 128 + tid] =
            sRed[w0 * 64 + tt * 16 + jc] + sRed[(w0 + 2) * 64 + tt * 16 + jc];
    }
}

// ---------------- K3: final small MLP ----------------
__global__ void k_final(const float* __restrict__ partials, const float* __restrict__ x,
                        const int* __restrict__ ip,
                        const float* __restrict__ e2n_w, const float* __restrict__ e2n_b,
                        const float* __restrict__ n2n_w, const float* __restrict__ n2n_b,
                        const float* __restrict__ out_w, const float* __restrict__ out_b,
                        float* __restrict__ out) {
    int b = blockIdx.x, j = threadIdx.x;  // 128 threads
    __shared__ float s0[128], s1[128], s2[128];
    float acc = 0.f;
    #pragma unroll
    for (int qq = 0; qq < 16; ++qq) acc += partials[(b * 16 + qq) * 128 + j];
    s0[j] = acc;
    __syncthreads();
    {
        float a1 = e2n_b[j];
        const float* w = e2n_w + j * 128;
        #pragma unroll 8
        for (int k = 0; k < 128; ++k) a1 += w[k] * s0[k];
        s1[j] = fmaxf(a1, 0.f);
    }
    __syncthreads();
    {
        float a2 = n2n_b[j];
        const float* w = n2n_w + j * 128;
        #pragma unroll 8
        for (int k = 0; k < 128; ++k) a2 += w[k] * s1[k];
        s2[j] = fmaxf(a2, 0.f);
    }
    __syncthreads();
    if (j < 64) {
        int i = ip[0];
        const float* xr = x + ((size_t)b * NN + i) * DIMX;
        const float* ow = out_w + j * 192;
        float o = out_b[j];
        #pragma unroll 8
        for (int m = 0; m < 64; ++m) o += ow[m] * xr[m];
        #pragma unroll 8
        for (int m = 0; m < 128; ++m) o += ow[64 + m] * s2[m];
        out[b * 64 + j] = o;
    }
}

extern "C" void kernel_launch(void* const* d_in, const int* in_sizes, int n_in,
                              void* d_out, int out_size, void* d_ws, size_t ws_size,
                              hipStream_t stream) {
    const float* x      = (const float*)d_in[0];
    const float* adj    = (const float*)d_in[1];
    const float* n2e_w  = (const float*)d_in[2];
    const float* n2e_b  = (const float*)d_in[3];
    const float* e2e_w  = (const float*)d_in[4];
    const float* e2e_b  = (const float*)d_in[5];
    const float* e2n_w  = (const float*)d_in[6];
    const float* e2n_b  = (const float*)d_in[7];
    const float* n2n_w  = (const float*)d_in[8];
    const float* n2n_b  = (const float*)d_in[9];
    const float* out_w  = (const float*)d_in[10];
    const float* out_b  = (const float*)d_in[11];
    const int*   ip     = (const int*)d_in[12];
    float* out = (float*)d_out;

    char* ws = (char*)d_ws;
    float* bias1    = (float*)ws;               // 16384 B
    u16*   w1p      = (u16*)(ws + 16384);       // 16384 B
    u16*   w2p      = (u16*)(ws + 32768);       // 32768 B
    float* partials = (float*)(ws + 65536);     // 262144 B (512 blocks * 128 f32)

    k_prep<<<112, 256, 0, stream>>>(x, n2e_w, n2e_b, e2e_w, ip, bias1, w1p, w2p);
    k_main<<<512, 256, 0, stream>>>(x, adj, bias1, w1p, w2p, e2e_b, partials);
    k_final<<<32, 128, 0, stream>>>(partials, x, ip, e2n_w, e2n_b, n2n_w, n2n_b,
                                    out_w, out_b, out);
}

// Round 10
// 46.994 us; speedup vs baseline: 2.8913x; 1.0418x over previous
//
#include <hip/hip_runtime.h>
#include <hip/hip_bf16.h>

typedef float f32x4 __attribute__((ext_vector_type(4)));
typedef short bf16x8 __attribute__((ext_vector_type(8)));
typedef unsigned short u16;
typedef unsigned int u32;

#define NB 32
#define NN 10000
#define DIMX 64

__device__ __forceinline__ u16 f2bf(float f) {
    union { float f; unsigned u; } v; v.f = f;
    unsigned r = (v.u + 0x7FFFu + ((v.u >> 16) & 1u)) >> 16;
    return (u16)r;
}

__device__ __forceinline__ u32 pkbf(float a, float b) {
    __hip_bfloat162 h = __float22bfloat162_rn(make_float2(a, b));
    u32 r; __builtin_memcpy(&r, &h, 4); return r;
}

// ---------------- K1: prep ----------------
__global__ void k_prep(const float* __restrict__ x, const float* __restrict__ n2e_w,
                       const float* __restrict__ n2e_b, const float* __restrict__ e2e_w,
                       const int* __restrict__ ip,
                       float* __restrict__ bias1, u16* __restrict__ w1p, u16* __restrict__ w2p) {
    int id = blockIdx.x * 256 + threadIdx.x;
    if (id < 4096) {
        int b = id >> 7, j = id & 127;
        int i = ip[0];
        const float* xr = x + ((size_t)b * NN + i) * DIMX;
        const float* w = n2e_w + j * 128 + 64;
        float s = n2e_b[j];
        #pragma unroll
        for (int d = 0; d < 64; ++d) s += xr[d] * w[d];
        bias1[b * 128 + j] = s;
    } else if (id < 12288) {
        int e = id - 4096;
        int i8 = e & 7, lane = (e >> 3) & 63, kk = (e >> 9) & 1, t = e >> 10;
        int row = t * 16 + (lane & 15), col = kk * 32 + (lane >> 4) * 8 + i8;
        w1p[e] = f2bf(n2e_w[row * 128 + col]);
    } else if (id < 28672) {
        int e = id - 12288;
        int i8 = e & 7, lane = (e >> 3) & 63, kk = (e >> 9) & 3, t = e >> 11;
        int row = t * 16 + (lane & 15), col = kk * 32 + (lane >> 4) * 8 + i8;
        w2p[e] = f2bf(e2e_w[row * 128 + col]);
    }
}

// ---------------- K2: main fused GEMM1(swapped)+GEMM2+reduce ----------------
// grid = 768 blocks (b = bid/24, qb = bid%24), 4 waves/block, 3 blocks/CU.
// Chunk qb0: 27 subtiles (16 rows each), else 26; 625 subtiles = 10000 rows.
// 7 iterations x 4 subtiles/block-iter. Phase-split per iteration:
//   GEMM1: each wave computes h1 for subtile==wave (4 kk2 slices -> sH1).
//   ONE barrier.
//   GEMM2: each wave reads all 4 subtiles' slices, accumulates its 2 private
//   t2 columns (W2 fragments persistent in 32 VGPRs -> no sW2 LDS).
// sH1 parity double-buffered => 1 barrier/iter total. acc[4][2] = 32 AGPRs.
// Waves own t2 exclusively -> direct partials write, no cross-wave reduce.
__global__ __launch_bounds__(256, 3) void k_main(
        const float* __restrict__ x, const float* __restrict__ adj,
        const float* __restrict__ bias1, const u16* __restrict__ w1p,
        const u16* __restrict__ w2p, const float* __restrict__ e2e_b,
        float* __restrict__ partials) {
    __shared__ u16 sW1[8192];     // 16 KB
    __shared__ u16 sH1[16384];    // 32 KB: [par2][kk2:4][sub:4][512 u16]
    __shared__ float sBias[256];  // [0:128) bias1 row b, [128:256) e2e_b

    const int tid = threadIdx.x;
    const int lane = tid & 63, wave = tid >> 6;
    const int c = lane & 15, g = lane >> 4;
    const int bid = blockIdx.x;
    const int b = bid / 24, qb = bid - b * 24;
    const int s0 = qb ? 27 + (qb - 1) * 26 : 0;
    const int cnt = qb ? 26 : 27;

    #pragma unroll
    for (int p = 0; p < 4; ++p) { int o = (p * 256 + tid) * 8;
        *(bf16x8*)&sW1[o] = *(const bf16x8*)&w1p[o]; }
    if (tid < 128) sBias[tid] = bias1[b * 128 + tid];
    else if (tid < 256) sBias[tid] = e2e_b[tid - 128];

    // W2 fragments for my 2 t2 columns: persistent registers (32 VGPRs)
    const bf16x8* const gW2 = (const bf16x8*)w2p;
    bf16x8 w2r[2][4];
    #pragma unroll
    for (int tt = 0; tt < 2; ++tt)
        #pragma unroll
        for (int kk2 = 0; kk2 < 4; ++kk2)
            w2r[tt][kk2] = gW2[((wave * 2 + tt) * 4 + kk2) * 64 + lane];

    float sAcc[2] = {0.f, 0.f};
    __syncthreads();

    const size_t xbatch = (size_t)b * NN;
    const int swzW = 16 * (c & 3);
    const int rdOff = (c * 64 + 16 * (g ^ (c & 3))) >> 1;   // u16 units

    // ---- prefetch iteration 0's x for my subtile (subtile index == wave) ----
    f32x4 xl[4];
    {
        int idx = wave;
        int stl = idx < cnt ? idx : cnt - 1;
        const float* xr = x + (xbatch + (s0 + stl) * 16 + c) * 64 + g * 8;
        xl[0] = *(const f32x4*)(xr);
        xl[1] = *(const f32x4*)(xr + 4);
        xl[2] = *(const f32x4*)(xr + 32);
        xl[3] = *(const f32x4*)(xr + 36);
    }

    int par = 0;
    #pragma unroll 1
    for (int it = 0; it < 7; ++it) {
        // ---- convert prefetched x to bf16 A-fragments ----
        bf16x8 A1[2];
        #pragma unroll
        for (int kk = 0; kk < 2; ++kk) {
            f32x4 lo = xl[kk * 2], hi = xl[kk * 2 + 1];
            union { bf16x8 v; u32 w[4]; } u;
            u.w[0] = pkbf(lo[0], lo[1]); u.w[1] = pkbf(lo[2], lo[3]);
            u.w[2] = pkbf(hi[0], hi[1]); u.w[3] = pkbf(hi[2], hi[3]);
            A1[kk] = u.v;
        }
        // ---- issue next iteration's x loads (hide under compute) ----
        if (it < 6) {
            int idx = (it + 1) * 4 + wave;
            int stl = idx < cnt ? idx : cnt - 1;
            const float* xr = x + (xbatch + (s0 + stl) * 16 + c) * 64 + g * 8;
            xl[0] = *(const f32x4*)(xr);
            xl[1] = *(const f32x4*)(xr + 4);
            xl[2] = *(const f32x4*)(xr + 32);
            xl[3] = *(const f32x4*)(xr + 36);
        }

        // ---- GEMM1 phase: my subtile, all 4 kk2 slices ----
        u16* const bufW = &sH1[par * 8192 + wave * 512];
        #pragma unroll
        for (int kk2 = 0; kk2 < 4; ++kk2) {
            const int t0 = kk2 * 2, t1 = kk2 * 2 + 1;
            bf16x8 w1a0 = *(const bf16x8*)&sW1[(t0 * 2 + 0) * 512 + lane * 8];
            bf16x8 w1b0 = *(const bf16x8*)&sW1[(t0 * 2 + 1) * 512 + lane * 8];
            bf16x8 w1a1 = *(const bf16x8*)&sW1[(t1 * 2 + 0) * 512 + lane * 8];
            bf16x8 w1b1 = *(const bf16x8*)&sW1[(t1 * 2 + 1) * 512 + lane * 8];
            f32x4 cb0 = *(const f32x4*)&sBias[t0 * 16 + 4 * g];
            f32x4 cb1 = *(const f32x4*)&sBias[t1 * 16 + 4 * g];
            f32x4 d0 = __builtin_amdgcn_mfma_f32_16x16x32_bf16(w1a0, A1[0], cb0, 0, 0, 0);
            d0 = __builtin_amdgcn_mfma_f32_16x16x32_bf16(w1b0, A1[1], d0, 0, 0, 0);
            f32x4 d1 = __builtin_amdgcn_mfma_f32_16x16x32_bf16(w1a1, A1[0], cb1, 0, 0, 0);
            d1 = __builtin_amdgcn_mfma_f32_16x16x32_bf16(w1b1, A1[1], d1, 0, 0, 0);
            u32 p00 = pkbf(fmaxf(d0[0], 0.f), fmaxf(d0[1], 0.f));
            u32 p01 = pkbf(fmaxf(d0[2], 0.f), fmaxf(d0[3], 0.f));
            u32 p10 = pkbf(fmaxf(d1[0], 0.f), fmaxf(d1[1], 0.f));
            u32 p11 = pkbf(fmaxf(d1[2], 0.f), fmaxf(d1[3], 0.f));
            int base = c * 64;
            *(uint2*)&bufW[kk2 * 2048 + ((base + ((8 * g) ^ swzW)) >> 1)]      = make_uint2(p00, p01);
            *(uint2*)&bufW[kk2 * 2048 + ((base + ((32 + 8 * g) ^ swzW)) >> 1)] = make_uint2(p10, p11);
        }
        __syncthreads();   // the ONLY barrier per iteration

        // ---- GEMM2 phase: all 4 subtiles, my 2 t2 columns ----
        f32x4 acc[4][2];   // 32 AGPRs
        #pragma unroll
        for (int sub = 0; sub < 4; ++sub)
            #pragma unroll
            for (int tt = 0; tt < 2; ++tt) acc[sub][tt] = (f32x4){0.f,0.f,0.f,0.f};
        const u16* const bufR = &sH1[par * 8192];
        #pragma unroll
        for (int kk2 = 0; kk2 < 4; ++kk2) {
            bf16x8 A2[4];
            #pragma unroll
            for (int sub = 0; sub < 4; ++sub)
                A2[sub] = *(const bf16x8*)&bufR[kk2 * 2048 + sub * 512 + rdOff];
            #pragma unroll
            for (int tt = 0; tt < 2; ++tt)
                #pragma unroll
                for (int sub = 0; sub < 4; ++sub)
                    acc[sub][tt] = __builtin_amdgcn_mfma_f32_16x16x32_bf16(A2[sub], w2r[tt][kk2], acc[sub][tt], 0, 0, 0);
        }

        // ---- epilogue: adj + bias2 + relu, weighted row sum ----
        f32x4 adjv[4];
        #pragma unroll
        for (int sub = 0; sub < 4; ++sub) {
            int idx = it * 4 + sub;
            if (idx < cnt) adjv[sub] = *(const f32x4*)(adj + (s0 + idx) * 16 + 4 * g);
            else adjv[sub] = (f32x4){0.f,0.f,0.f,0.f};
        }
        #pragma unroll
        for (int tt = 0; tt < 2; ++tt) {
            float bb = sBias[128 + (wave * 2 + tt) * 16 + c];
            #pragma unroll
            for (int sub = 0; sub < 4; ++sub)
                #pragma unroll
                for (int r = 0; r < 4; ++r)
                    sAcc[tt] = fmaf(adjv[sub][r], fmaxf(acc[sub][tt][r] + bb, 0.f), sAcc[tt]);
        }
        par ^= 1;
    }

    // reduce over lane-groups (g); waves own their t2 -> direct global write
    float red[2];
    #pragma unroll
    for (int tt = 0; tt < 2; ++tt) {
        float v = sAcc[tt];
        v += __shfl_xor(v, 16, 64);
        v += __shfl_xor(v, 32, 64);
        red[tt] = v;
    }
    if (lane < 16) {
        #pragma unroll
        for (int tt = 0; tt < 2; ++tt)
            partials[bid * 128 + (wave * 2 + tt) * 16 + lane] = red[tt];
    }
}

// ---------------- K3: final small MLP ----------------
__global__ void k_final(const float* __restrict__ partials, const float* __restrict__ x,
                        const int* __restrict__ ip,
                        const float* __restrict__ e2n_w, const float* __restrict__ e2n_b,
                        const float* __restrict__ n2n_w, const float* __restrict__ n2n_b,
                        const float* __restrict__ out_w, const float* __restrict__ out_b,
                        float* __restrict__ out) {
    int b = blockIdx.x, j = threadIdx.x;  // 128 threads
    __shared__ float s0[128], s1[128], s2[128];
    float acc = 0.f;
    #pragma unroll
    for (int qq = 0; qq < 24; ++qq) acc += partials[(b * 24 + qq) * 128 + j];
    s0[j] = acc;
    __syncthreads();
    {
        float a1 = e2n_b[j];
        const float* w = e2n_w + j * 128;
        #pragma unroll 8
        for (int k = 0; k < 128; ++k) a1 += w[k] * s0[k];
        s1[j] = fmaxf(a1, 0.f);
    }
    __syncthreads();
    {
        float a2 = n2n_b[j];
        const float* w = n2n_w + j * 128;
        #pragma unroll 8
        for (int k = 0; k < 128; ++k) a2 += w[k] * s1[k];
        s2[j] = fmaxf(a2, 0.f);
    }
    __syncthreads();
    if (j < 64) {
        int i = ip[0];
        const float* xr = x + ((size_t)b * NN + i) * DIMX;
        const float* ow = out_w + j * 192;
        float o = out_b[j];
        #pragma unroll 8
        for (int m = 0; m < 64; ++m) o += ow[m] * xr[m];
        #pragma unroll 8
        for (int m = 0; m < 128; ++m) o += ow[64 + m] * s2[m];
        out[b * 64 + j] = o;
    }
}

extern "C" void kernel_launch(void* const* d_in, const int* in_sizes, int n_in,
                              void* d_out, int out_size, void* d_ws, size_t ws_size,
                              hipStream_t stream) {
    const float* x      = (const float*)d_in[0];
    const float* adj    = (const float*)d_in[1];
    const float* n2e_w  = (const float*)d_in[2];
    const float* n2e_b  = (const float*)d_in[3];
    const float* e2e_w  = (const float*)d_in[4];
    const float* e2e_b  = (const float*)d_in[5];
    const float* e2n_w  = (const float*)d_in[6];
    const float* e2n_b  = (const float*)d_in[7];
    const float* n2n_w  = (const float*)d_in[8];
    const float* n2n_b  = (const float*)d_in[9];
    const float* out_w  = (const float*)d_in[10];
    const float* out_b  = (const float*)d_in[11];
    const int*   ip     = (const int*)d_in[12];
    float* out = (float*)d_out;

    char* ws = (char*)d_ws;
    float* bias1    = (float*)ws;               // 16384 B
    u16*   w1p      = (u16*)(ws + 16384);       // 16384 B
    u16*   w2p      = (u16*)(ws + 32768);       // 32768 B
    float* partials = (float*)(ws + 65536);     // 393216 B (768 blocks * 128 f32)

    k_prep<<<112, 256, 0, stream>>>(x, n2e_w, n2e_b, e2e_w, ip, bias1, w1p, w2p);
    k_main<<<768, 256, 0, stream>>>(x, adj, bias1, w1p, w2p, e2e_b, partials);
    k_final<<<32, 128, 0, stream>>>(partials, x, ip, e2n_w, e2n_b, n2n_w, n2n_b,
                                    out_w, out_b, out);
}